// Round 1
// baseline (1427.333 us; speedup 1.0000x reference)
//
#include <hip/hip_runtime.h>
#include <math.h>

// Problem constants
#define NB   32
#define NP   128
#define NM   4096        // NB*NP matrices per type
#define NMAT3 12288      // 3*NM (Q,K,V)

// ---------------------------------------------------------------------------
// K1: bimap — Q/K/V[b,p] = W * x[b,p] * W^T   (x: 64x64 SPD, W: 32x64)
// one block per (b,p); LDS-staged S, W, T.
// ---------------------------------------------------------------------------
__global__ __launch_bounds__(256) void bimap_kernel(
    const float* __restrict__ x, const float* __restrict__ Wq,
    const float* __restrict__ Wk, const float* __restrict__ Wv,
    float* __restrict__ qkv)
{
    __shared__ __align__(16) float S[64 * 64];
    __shared__ float Wl[32 * 65];   // pad 65: row reads conflict-free
    __shared__ float T[32 * 65];
    const int tid = threadIdx.x;
    const int bp  = blockIdx.x;
    const float* xs = x + (size_t)bp * 4096;
    // load S (64x64), float4 coalesced
#pragma unroll
    for (int k = 0; k < 4; ++k) {
        int idx = tid * 4 + k * 1024;
        *(float4*)&S[idx] = *(const float4*)&xs[idx];
    }
    const int o32 = tid & 31;
    const int grp = tid >> 5;
#pragma unroll 1
    for (int w = 0; w < 3; ++w) {
        const float* Wsrc = (w == 0) ? Wq : ((w == 1) ? Wk : Wv);
        __syncthreads();   // prev-iter readers of Wl/T done; S visible (w=0)
#pragma unroll
        for (int k = 0; k < 8; ++k) {
            int f = tid + k * 256;
            Wl[(f >> 6) * 65 + (f & 63)] = Wsrc[f];
        }
        __syncthreads();
        // T = W * S : thread (o32, grp) computes T[o32][grp*8 .. +7]
        {
            float acc[8];
#pragma unroll
            for (int jj = 0; jj < 8; ++jj) acc[jj] = 0.f;
            const int j0 = grp * 8;
#pragma unroll 4
            for (int i = 0; i < 64; ++i) {
                float wv = Wl[o32 * 65 + i];
                const float4 s0 = *(const float4*)&S[i * 64 + j0];
                const float4 s1 = *(const float4*)&S[i * 64 + j0 + 4];
                acc[0] = fmaf(wv, s0.x, acc[0]);
                acc[1] = fmaf(wv, s0.y, acc[1]);
                acc[2] = fmaf(wv, s0.z, acc[2]);
                acc[3] = fmaf(wv, s0.w, acc[3]);
                acc[4] = fmaf(wv, s1.x, acc[4]);
                acc[5] = fmaf(wv, s1.y, acc[5]);
                acc[6] = fmaf(wv, s1.z, acc[6]);
                acc[7] = fmaf(wv, s1.w, acc[7]);
            }
#pragma unroll
            for (int jj = 0; jj < 8; ++jj) T[o32 * 65 + j0 + jj] = acc[jj];
        }
        __syncthreads();
        // out = T * W^T : thread (kcol=tid&31, grp) computes out[grp*4+cc][kcol]
        {
            float oacc[4] = {0.f, 0.f, 0.f, 0.f};
            const int kcol = tid & 31;
            const int ob   = grp * 4;
#pragma unroll 4
            for (int j = 0; j < 64; ++j) {
                float wv = Wl[kcol * 65 + j];   // conflict-free: (kcol+j)%32 distinct
#pragma unroll
                for (int cc = 0; cc < 4; ++cc)
                    oacc[cc] = fmaf(T[(ob + cc) * 65 + j], wv, oacc[cc]);  // broadcast
            }
            float* dst = qkv + ((size_t)w * NM + bp) * 1024;
#pragma unroll
            for (int cc = 0; cc < 4; ++cc)
                dst[(ob + cc) * 32 + kcol] = oacc[cc];   // coalesced
        }
    }
}

// ---------------------------------------------------------------------------
// K2/K5: batched symmetric eig-function via one-sided (Hestenes) Jacobi.
// Lane owns column `col` of one 32x32 matrix (all in registers); 2 matrices
// per wave64, 8 per 256-thread block. After convergence: lambda_j = ||col_j||,
// u_j = col_j / lambda_j ; out = U f(Lambda) U^T.
// MODE 0: f = log(lambda), also writes ssq = ||out||_F^2  (in==out allowed)
// MODE 1: input += shift*I on load, f = exp(lambda - shift)
// ---------------------------------------------------------------------------
template <int MODE>
__global__ __launch_bounds__(256) void eig_fn_kernel(
    const float* in, float* out, float* __restrict__ ssq, float shift)
{
    __shared__ __align__(16) float Uld[8][32 * 36];
    __shared__ __align__(16) float fld[8][32];
    const int tid      = threadIdx.x;
    const int slot     = tid >> 5;          // matrix slot in block (0..7)
    const int col      = tid & 31;          // column this lane owns
    const int laneBase = (tid & 63) & 32;   // 0 or 32: half-wave base
    const size_t midx  = (size_t)blockIdx.x * 8 + slot;

    const float* src = in + midx * 1024;
    float a[32];
#pragma unroll
    for (int i = 0; i < 32; ++i) {
        float v = src[i * 32 + col];
        if (MODE == 1) v += (i == col) ? shift : 0.0f;
        a[i] = v;
    }

    // ---- one-sided Jacobi sweeps ----
    for (int sweep = 0; sweep < 20; ++sweep) {
        float alpha = 0.f;                      // ||own col||^2, tracked in-round
#pragma unroll
        for (int i = 0; i < 32; ++i) alpha = fmaf(a[i], a[i], alpha);
        bool anyrot = false;
        for (int r = 0; r < 31; ++r) {
            // round-robin partner: circle method, col 31 fixed
            int pcol;
            if (col == 31)      pcol = r;
            else if (col == r)  pcol = 31;
            else {
                int v = 2 * r - col;
                pcol = (v < 0) ? v + 31 : (v >= 31 ? v - 31 : v);
            }
            const int plane = laneBase + pcol;
            float t[32];
#pragma unroll
            for (int i = 0; i < 32; ++i) t[i] = __shfl(a[i], plane);
            float gamma = 0.f;
#pragma unroll
            for (int i = 0; i < 32; ++i) gamma = fmaf(a[i], t[i], gamma);
            const float beta = __shfl(alpha, plane);
            const bool  isP  = col < pcol;
            const float ap   = isP ? alpha : beta;
            const float aq   = isP ? beta : alpha;
            const bool doRot = (gamma * gamma > 1e-14f * ap * aq);
            anyrot |= doRot;
            const float zeta = (aq - ap) / (2.0f * gamma);
            float tt = copysignf(1.0f / (fabsf(zeta) + sqrtf(fmaf(zeta, zeta, 1.0f))), zeta);
            float c  = 1.0f / sqrtf(fmaf(tt, tt, 1.0f));
            float s  = c * tt;
            c = doRot ? c : 1.0f;       // NaN-safe select when gamma==0
            s = doRot ? s : 0.0f;
            const float ssn = isP ? -s : s;
#pragma unroll
            for (int i = 0; i < 32; ++i) a[i] = fmaf(c, a[i], ssn * t[i]);
            alpha = c * c * alpha + s * s * beta + 2.0f * c * ssn * gamma;
        }
        if (!__any((int)anyrot)) break;   // all pairs orthogonal -> converged
    }

    // ---- reconstruction: out = U f(S) U^T ----
    float s2 = 0.f;
#pragma unroll
    for (int i = 0; i < 32; ++i) s2 = fmaf(a[i], a[i], s2);
    const float sigma = sqrtf(s2);
    const float invs  = 1.0f / fmaxf(sigma, 1e-30f);
    float fv;
    if (MODE == 0) fv = 0.5f * logf(fmaxf(s2, 1e-38f));   // log(sigma)
    else           fv = expf(sigma - shift);

    float* U = &Uld[slot][0];
#pragma unroll
    for (int i = 0; i < 32; ++i) U[i * 36 + col] = a[i] * invs;  // (i+col)%32: no conflict
    fld[slot][col] = fv;
    __syncthreads();

    float rr[32];   // row `col` of U, pre-scaled by f
#pragma unroll
    for (int m = 0; m < 32; ++m) rr[m] = U[col * 36 + m] * fld[slot][m];

    float* dst = out + midx * 1024;
    float sq = 0.f;
#pragma unroll
    for (int i = 0; i < 32; ++i) {
        float acc = 0.f;
        const float4* urow = (const float4*)&U[i * 36];   // broadcast b128 reads
#pragma unroll
        for (int m4 = 0; m4 < 8; ++m4) {
            float4 u4 = urow[m4];
            acc = fmaf(u4.x, rr[m4 * 4 + 0], acc);
            acc = fmaf(u4.y, rr[m4 * 4 + 1], acc);
            acc = fmaf(u4.z, rr[m4 * 4 + 2], acc);
            acc = fmaf(u4.w, rr[m4 * 4 + 3], acc);
        }
        dst[i * 32 + col] = acc;    // coalesced
        sq = fmaf(acc, acc, sq);
    }
    if (MODE == 0) {
#pragma unroll
        for (int off = 1; off < 32; off <<= 1) sq += __shfl_xor(sq, off, 32);
        if (col == 0) ssq[midx] = sq;
    }
}

// ---------------------------------------------------------------------------
// K3a: weights[b,q,k] = 1/(1+log1p(max(qq+kk-2*<LQ_q,LK_k>_F, 0)))
// GEMM over m=1024, 32x32 output tile per block, 2x2 per thread.
// ---------------------------------------------------------------------------
__global__ __launch_bounds__(256) void qk_weights_kernel(
    const float* __restrict__ L, const float* __restrict__ ssq,
    float* __restrict__ wbuf)
{
    __shared__ float Aq[32 * 37];
    __shared__ float Bk[32 * 37];
    const int b  = blockIdx.z;
    const int q0 = blockIdx.y * 32;
    const int k0 = blockIdx.x * 32;
    const int tid = threadIdx.x;
    const int tx = tid & 15, ty = tid >> 4;
    const float* LQ = L + ((size_t)b * 128 + q0) * 1024;
    const float* LK = L + (size_t)NM * 1024 + ((size_t)b * 128 + k0) * 1024;
    const int lrow = tid >> 3;
    const int lm4  = (tid & 7) * 4;
    float acc00 = 0, acc01 = 0, acc10 = 0, acc11 = 0;
    for (int m0 = 0; m0 < 1024; m0 += 32) {
        __syncthreads();
        float4 va = *(const float4*)&LQ[(size_t)lrow * 1024 + m0 + lm4];
        float4 vb = *(const float4*)&LK[(size_t)lrow * 1024 + m0 + lm4];
        Aq[lrow * 37 + lm4 + 0] = va.x; Aq[lrow * 37 + lm4 + 1] = va.y;
        Aq[lrow * 37 + lm4 + 2] = va.z; Aq[lrow * 37 + lm4 + 3] = va.w;
        Bk[lrow * 37 + lm4 + 0] = vb.x; Bk[lrow * 37 + lm4 + 1] = vb.y;
        Bk[lrow * 37 + lm4 + 2] = vb.z; Bk[lrow * 37 + lm4 + 3] = vb.w;
        __syncthreads();
#pragma unroll
        for (int mm = 0; mm < 32; ++mm) {
            float a0 = Aq[(ty * 2 + 0) * 37 + mm];
            float a1 = Aq[(ty * 2 + 1) * 37 + mm];
            float b0 = Bk[(tx * 2 + 0) * 37 + mm];
            float b1 = Bk[(tx * 2 + 1) * 37 + mm];
            acc00 = fmaf(a0, b0, acc00); acc01 = fmaf(a0, b1, acc01);
            acc10 = fmaf(a1, b0, acc10); acc11 = fmaf(a1, b1, acc11);
        }
    }
    const float* qqp = ssq + (size_t)b * 128 + q0;
    const float* kkp = ssq + NM + (size_t)b * 128 + k0;
    const int q = ty * 2, k = tx * 2;
    float* wrow0 = wbuf + ((size_t)b * 128 + q0 + q) * 128 + k0 + k;
    float* wrow1 = wrow0 + 128;
    float e;
    e = fmaxf(qqp[q] + kkp[k] - 2.0f * acc00, 0.0f);
    wrow0[0] = 1.0f / (1.0f + log1pf(e));
    e = fmaxf(qqp[q] + kkp[k + 1] - 2.0f * acc01, 0.0f);
    wrow0[1] = 1.0f / (1.0f + log1pf(e));
    e = fmaxf(qqp[q + 1] + kkp[k] - 2.0f * acc10, 0.0f);
    wrow1[0] = 1.0f / (1.0f + log1pf(e));
    e = fmaxf(qqp[q + 1] + kkp[k + 1] - 2.0f * acc11, 0.0f);
    wrow1[1] = 1.0f / (1.0f + log1pf(e));
}

// ---------------------------------------------------------------------------
// K3b: in-place softmax over the QUERY axis (column-wise on [q][k]),
// one block per b. weights in (0,1] -> no max subtraction needed.
// ---------------------------------------------------------------------------
__global__ __launch_bounds__(256) void softmax_kernel(float* __restrict__ wbuf)
{
    __shared__ float crcp[128];
    const int t = threadIdx.x;
    float* wb = wbuf + (size_t)blockIdx.x * 16384;
    if (t < 128) {
        float ssum = 0.f;
        for (int q = 0; q < 128; ++q) ssum += expf(wb[q * 128 + t]);
        crcp[t] = 1.0f / ssum;
    }
    __syncthreads();
    for (int i = t; i < 16384; i += 256)
        wb[i] = expf(wb[i]) * crcp[i & 127];
}

// ---------------------------------------------------------------------------
// K4: mean_log[b,i,:] = sum_j soft[b,j,i] * LV[b,j,:]
// A = soft^T staged with transpose into LDS; B = LV streamed in 32-row chunks.
// Writes ML over the (dead) LQ region.
// ---------------------------------------------------------------------------
__global__ __launch_bounds__(256) void meanlog_kernel(
    const float* __restrict__ soft, const float* __restrict__ LV,
    float* __restrict__ ML)
{
    __shared__ float Wt[32 * 129];              // [i][j]
    __shared__ __align__(16) float Bl[32 * 260]; // [j][c]
    const int b  = blockIdx.z;
    const int i0 = blockIdx.y * 32;
    const int c0 = blockIdx.x * 256;
    const int t  = threadIdx.x;
    const float* sp = soft + (size_t)b * 16384;
#pragma unroll
    for (int jb = 0; jb < 4; ++jb) {
        int j  = jb * 32 + (t >> 3);
        int i4 = (t & 7) * 4;
        float4 v = *(const float4*)&sp[(size_t)j * 128 + i0 + i4];
        Wt[(i4 + 0) * 129 + j] = v.x;
        Wt[(i4 + 1) * 129 + j] = v.y;
        Wt[(i4 + 2) * 129 + j] = v.z;
        Wt[(i4 + 3) * 129 + j] = v.w;
    }
    float acc[32];
#pragma unroll
    for (int i = 0; i < 32; ++i) acc[i] = 0.f;
    const float* lv = LV + (size_t)2 * NM * 1024 + (size_t)b * 128 * 1024 + c0;
    for (int j0 = 0; j0 < 128; j0 += 32) {
        __syncthreads();   // covers Wt writes (first iter) + Bl reuse
#pragma unroll
        for (int jj8 = 0; jj8 < 8; ++jj8) {
            int j  = jj8 * 4 + (t >> 6);
            int c4 = (t & 63) * 4;
            *(float4*)&Bl[j * 260 + c4] =
                *(const float4*)&lv[(size_t)(j0 + j) * 1024 + c4];
        }
        __syncthreads();
#pragma unroll
        for (int jj = 0; jj < 32; ++jj) {
            float v = Bl[jj * 260 + t];
#pragma unroll
            for (int i = 0; i < 32; ++i)
                acc[i] = fmaf(Wt[i * 129 + j0 + jj], v, acc[i]);   // broadcast
        }
    }
    float* mp = ML + ((size_t)b * 128 + i0) * 1024 + c0;
#pragma unroll
    for (int i = 0; i < 32; ++i) mp[(size_t)i * 1024 + t] = acc[i];
}

// ---------------------------------------------------------------------------
// launcher
// ws layout (floats): [0, 3*NM*1024) qkv -> logs in place (region0 reused as ML)
//                     [+0, 16384)     ssq (qq,kk,(vv))
//                     [+, NM*128)     weights/soft (in-place softmax)
// total ~50.1 MB
// ---------------------------------------------------------------------------
extern "C" void kernel_launch(void* const* d_in, const int* in_sizes, int n_in,
                              void* d_out, int out_size, void* d_ws, size_t ws_size,
                              hipStream_t stream)
{
    const float* x  = (const float*)d_in[0];
    const float* Wq = (const float*)d_in[1];
    const float* Wk = (const float*)d_in[2];
    const float* Wv = (const float*)d_in[3];
    float* ws   = (float*)d_ws;
    float* qkv  = ws;                               // 3*NM*1024
    float* ssqp = ws + (size_t)3 * NM * 1024;       // 12288 (padded 16384)
    float* wbuf = ssqp + 16384;                     // NM*128
    float* out  = (float*)d_out;

    bimap_kernel<<<NM, 256, 0, stream>>>(x, Wq, Wk, Wv, qkv);
    eig_fn_kernel<0><<<NMAT3 / 8, 256, 0, stream>>>(qkv, qkv, ssqp, 0.0f);
    qk_weights_kernel<<<dim3(4, 4, 32), 256, 0, stream>>>(qkv, ssqp, wbuf);
    softmax_kernel<<<32, 256, 0, stream>>>(wbuf);
    meanlog_kernel<<<dim3(4, 4, 32), 256, 0, stream>>>(wbuf, qkv, qkv);
    eig_fn_kernel<1><<<NM / 8, 256, 0, stream>>>(qkv, out, nullptr, 16.0f);
}

// Round 2
// 1217.860 us; speedup vs baseline: 1.1720x; 1.1720x over previous
//
#include <hip/hip_runtime.h>
#include <math.h>

// Problem constants
#define NB   32
#define NP   128
#define NM   4096        // NB*NP matrices per type
#define NMAT3 12288      // 3*NM (Q,K,V)

// ---------------------------------------------------------------------------
// K1: bimap — Q/K/V[b,p] = W * x[b,p] * W^T   (x: 64x64 SPD, W: 32x64)
// one block per (b,p); LDS-staged S, W, T.
// ---------------------------------------------------------------------------
__global__ __launch_bounds__(256) void bimap_kernel(
    const float* __restrict__ x, const float* __restrict__ Wq,
    const float* __restrict__ Wk, const float* __restrict__ Wv,
    float* __restrict__ qkv)
{
    __shared__ __align__(16) float S[64 * 64];
    __shared__ float Wl[32 * 65];   // pad 65: row reads conflict-free
    __shared__ float T[32 * 65];
    const int tid = threadIdx.x;
    const int bp  = blockIdx.x;
    const float* xs = x + (size_t)bp * 4096;
    // load S (64x64), float4 coalesced
#pragma unroll
    for (int k = 0; k < 4; ++k) {
        int idx = tid * 4 + k * 1024;
        *(float4*)&S[idx] = *(const float4*)&xs[idx];
    }
    const int o32 = tid & 31;
    const int grp = tid >> 5;
#pragma unroll 1
    for (int w = 0; w < 3; ++w) {
        const float* Wsrc = (w == 0) ? Wq : ((w == 1) ? Wk : Wv);
        __syncthreads();   // prev-iter readers of Wl/T done; S visible (w=0)
#pragma unroll
        for (int k = 0; k < 8; ++k) {
            int f = tid + k * 256;
            Wl[(f >> 6) * 65 + (f & 63)] = Wsrc[f];
        }
        __syncthreads();
        // T = W * S : thread (o32, grp) computes T[o32][grp*8 .. +7]
        {
            float acc[8];
#pragma unroll
            for (int jj = 0; jj < 8; ++jj) acc[jj] = 0.f;
            const int j0 = grp * 8;
#pragma unroll 4
            for (int i = 0; i < 64; ++i) {
                float wv = Wl[o32 * 65 + i];
                const float4 s0 = *(const float4*)&S[i * 64 + j0];
                const float4 s1 = *(const float4*)&S[i * 64 + j0 + 4];
                acc[0] = fmaf(wv, s0.x, acc[0]);
                acc[1] = fmaf(wv, s0.y, acc[1]);
                acc[2] = fmaf(wv, s0.z, acc[2]);
                acc[3] = fmaf(wv, s0.w, acc[3]);
                acc[4] = fmaf(wv, s1.x, acc[4]);
                acc[5] = fmaf(wv, s1.y, acc[5]);
                acc[6] = fmaf(wv, s1.z, acc[6]);
                acc[7] = fmaf(wv, s1.w, acc[7]);
            }
#pragma unroll
            for (int jj = 0; jj < 8; ++jj) T[o32 * 65 + j0 + jj] = acc[jj];
        }
        __syncthreads();
        // out = T * W^T : thread (kcol=tid&31, grp) computes out[grp*4+cc][kcol]
        {
            float oacc[4] = {0.f, 0.f, 0.f, 0.f};
            const int kcol = tid & 31;
            const int ob   = grp * 4;
#pragma unroll 4
            for (int j = 0; j < 64; ++j) {
                float wv = Wl[kcol * 65 + j];   // conflict-free: (kcol+j)%32 distinct
#pragma unroll
                for (int cc = 0; cc < 4; ++cc)
                    oacc[cc] = fmaf(T[(ob + cc) * 65 + j], wv, oacc[cc]);  // broadcast
            }
            float* dst = qkv + ((size_t)w * NM + bp) * 1024;
#pragma unroll
            for (int cc = 0; cc < 4; ++cc)
                dst[(ob + cc) * 32 + kcol] = oacc[cc];   // coalesced
        }
    }
}

// ---------------------------------------------------------------------------
// K2/K5: batched symmetric eig-function via one-sided (Hestenes) Jacobi.
// Lane owns column `col` of one 32x32 matrix (all in registers); 2 matrices
// per wave64 = per 64-thread block (small LDS -> high occupancy).
// After convergence: lambda_j = ||col_j||, u_j = col_j / lambda_j;
// out = U f(Lambda) U^T.
// MODE 0: f = log(lambda), also writes ssq = ||out||_F^2  (in==out allowed)
// MODE 1: input += shift*I on load, f = exp(lambda - shift)
//
// Convergence: early-exit threshold is RELATIVE, gamma^2 > 1e-12*ap*aq
// (|cos angle| > 1e-6). 1e-14 sits at the fp32 noise floor and never
// quiesces (R1 counters: full 20 sweeps, DS-pipe-bound at ~1 ms).
// One-sided Jacobi has high *relative* accuracy, so 1e-6 angle error gives
// log-reconstruction error ~ 3e-5 << 0.022 tolerance.
// ---------------------------------------------------------------------------
template <int MODE>
__global__ __launch_bounds__(64) void eig_fn_kernel(
    const float* in, float* out, float* __restrict__ ssq, float shift)
{
    __shared__ __align__(16) float Uld[2][32 * 36];
    __shared__ __align__(16) float fld[2][32];
    const int tid      = threadIdx.x;
    const int slot     = tid >> 5;          // matrix slot in block (0..1)
    const int col      = tid & 31;          // column this lane owns
    const int laneBase = tid & 32;          // 0 or 32: half-wave base
    const size_t midx  = (size_t)blockIdx.x * 2 + slot;

    const float* src = in + midx * 1024;
    float a[32];
#pragma unroll
    for (int i = 0; i < 32; ++i) {
        float v = src[i * 32 + col];
        if (MODE == 1) v += (i == col) ? shift : 0.0f;
        a[i] = v;
    }

    // ---- one-sided Jacobi sweeps ----
    for (int sweep = 0; sweep < 12; ++sweep) {
        float alpha = 0.f;                      // ||own col||^2, tracked in-round
#pragma unroll
        for (int i = 0; i < 32; ++i) alpha = fmaf(a[i], a[i], alpha);
        bool anyrot = false;
        for (int r = 0; r < 31; ++r) {
            // round-robin partner: circle method, col 31 fixed
            int pcol;
            if (col == 31)      pcol = r;
            else if (col == r)  pcol = 31;
            else {
                int v = 2 * r - col;
                pcol = (v < 0) ? v + 31 : (v >= 31 ? v - 31 : v);
            }
            const int plane = laneBase + pcol;
            float t[32];
#pragma unroll
            for (int i = 0; i < 32; ++i) t[i] = __shfl(a[i], plane);
            float gamma = 0.f;
#pragma unroll
            for (int i = 0; i < 32; ++i) gamma = fmaf(a[i], t[i], gamma);
            const float beta = __shfl(alpha, plane);
            const bool  isP  = col < pcol;
            const float ap   = isP ? alpha : beta;
            const float aq   = isP ? beta : alpha;
            const bool doRot = (gamma * gamma > 1e-12f * ap * aq);
            anyrot |= doRot;
            const float zeta = (aq - ap) / (2.0f * gamma);
            float tt = copysignf(1.0f / (fabsf(zeta) + sqrtf(fmaf(zeta, zeta, 1.0f))), zeta);
            float c  = 1.0f / sqrtf(fmaf(tt, tt, 1.0f));
            float s  = c * tt;
            c = doRot ? c : 1.0f;       // NaN-safe select when gamma==0
            s = doRot ? s : 0.0f;
            const float ssn = isP ? -s : s;
#pragma unroll
            for (int i = 0; i < 32; ++i) a[i] = fmaf(c, a[i], ssn * t[i]);
            alpha = c * c * alpha + s * s * beta + 2.0f * c * ssn * gamma;
        }
        if (!__any((int)anyrot)) break;   // all pairs orthogonal -> converged
    }

    // ---- reconstruction: out = U f(S) U^T ----
    float s2 = 0.f;
#pragma unroll
    for (int i = 0; i < 32; ++i) s2 = fmaf(a[i], a[i], s2);
    const float sigma = sqrtf(s2);
    const float invs  = 1.0f / fmaxf(sigma, 1e-30f);
    float fv;
    if (MODE == 0) fv = 0.5f * logf(fmaxf(s2, 1e-38f));   // log(sigma)
    else           fv = expf(sigma - shift);

    float* U = &Uld[slot][0];
#pragma unroll
    for (int i = 0; i < 32; ++i) U[i * 36 + col] = a[i] * invs;  // (i+col)%32: no conflict
    fld[slot][col] = fv;
    __syncthreads();

    float rr[32];   // row `col` of U, pre-scaled by f
#pragma unroll
    for (int m = 0; m < 32; ++m) rr[m] = U[col * 36 + m] * fld[slot][m];

    float* dst = out + midx * 1024;
    float sq = 0.f;
#pragma unroll
    for (int i = 0; i < 32; ++i) {
        float acc = 0.f;
        const float4* urow = (const float4*)&U[i * 36];   // broadcast b128 reads
#pragma unroll
        for (int m4 = 0; m4 < 8; ++m4) {
            float4 u4 = urow[m4];
            acc = fmaf(u4.x, rr[m4 * 4 + 0], acc);
            acc = fmaf(u4.y, rr[m4 * 4 + 1], acc);
            acc = fmaf(u4.z, rr[m4 * 4 + 2], acc);
            acc = fmaf(u4.w, rr[m4 * 4 + 3], acc);
        }
        dst[i * 32 + col] = acc;    // coalesced
        sq = fmaf(acc, acc, sq);
    }
    if (MODE == 0) {
#pragma unroll
        for (int off = 1; off < 32; off <<= 1) sq += __shfl_xor(sq, off, 32);
        if (col == 0) ssq[midx] = sq;
    }
}

// ---------------------------------------------------------------------------
// K3a: weights[b,q,k] = 1/(1+log1p(max(qq+kk-2*<LQ_q,LK_k>_F, 0)))
// GEMM over m=1024, 32x32 output tile per block, 2x2 per thread.
// ---------------------------------------------------------------------------
__global__ __launch_bounds__(256) void qk_weights_kernel(
    const float* __restrict__ L, const float* __restrict__ ssq,
    float* __restrict__ wbuf)
{
    __shared__ float Aq[32 * 37];
    __shared__ float Bk[32 * 37];
    const int b  = blockIdx.z;
    const int q0 = blockIdx.y * 32;
    const int k0 = blockIdx.x * 32;
    const int tid = threadIdx.x;
    const int tx = tid & 15, ty = tid >> 4;
    const float* LQ = L + ((size_t)b * 128 + q0) * 1024;
    const float* LK = L + (size_t)NM * 1024 + ((size_t)b * 128 + k0) * 1024;
    const int lrow = tid >> 3;
    const int lm4  = (tid & 7) * 4;
    float acc00 = 0, acc01 = 0, acc10 = 0, acc11 = 0;
    for (int m0 = 0; m0 < 1024; m0 += 32) {
        __syncthreads();
        float4 va = *(const float4*)&LQ[(size_t)lrow * 1024 + m0 + lm4];
        float4 vb = *(const float4*)&LK[(size_t)lrow * 1024 + m0 + lm4];
        Aq[lrow * 37 + lm4 + 0] = va.x; Aq[lrow * 37 + lm4 + 1] = va.y;
        Aq[lrow * 37 + lm4 + 2] = va.z; Aq[lrow * 37 + lm4 + 3] = va.w;
        Bk[lrow * 37 + lm4 + 0] = vb.x; Bk[lrow * 37 + lm4 + 1] = vb.y;
        Bk[lrow * 37 + lm4 + 2] = vb.z; Bk[lrow * 37 + lm4 + 3] = vb.w;
        __syncthreads();
#pragma unroll
        for (int mm = 0; mm < 32; ++mm) {
            float a0 = Aq[(ty * 2 + 0) * 37 + mm];
            float a1 = Aq[(ty * 2 + 1) * 37 + mm];
            float b0 = Bk[(tx * 2 + 0) * 37 + mm];
            float b1 = Bk[(tx * 2 + 1) * 37 + mm];
            acc00 = fmaf(a0, b0, acc00); acc01 = fmaf(a0, b1, acc01);
            acc10 = fmaf(a1, b0, acc10); acc11 = fmaf(a1, b1, acc11);
        }
    }
    const float* qqp = ssq + (size_t)b * 128 + q0;
    const float* kkp = ssq + NM + (size_t)b * 128 + k0;
    const int q = ty * 2, k = tx * 2;
    float* wrow0 = wbuf + ((size_t)b * 128 + q0 + q) * 128 + k0 + k;
    float* wrow1 = wrow0 + 128;
    float e;
    e = fmaxf(qqp[q] + kkp[k] - 2.0f * acc00, 0.0f);
    wrow0[0] = 1.0f / (1.0f + log1pf(e));
    e = fmaxf(qqp[q] + kkp[k + 1] - 2.0f * acc01, 0.0f);
    wrow0[1] = 1.0f / (1.0f + log1pf(e));
    e = fmaxf(qqp[q + 1] + kkp[k] - 2.0f * acc10, 0.0f);
    wrow1[0] = 1.0f / (1.0f + log1pf(e));
    e = fmaxf(qqp[q + 1] + kkp[k + 1] - 2.0f * acc11, 0.0f);
    wrow1[1] = 1.0f / (1.0f + log1pf(e));
}

// ---------------------------------------------------------------------------
// K3b: in-place softmax over the QUERY axis (column-wise on [q][k]),
// one block per b. weights in (0,1] -> no max subtraction needed.
// ---------------------------------------------------------------------------
__global__ __launch_bounds__(256) void softmax_kernel(float* __restrict__ wbuf)
{
    __shared__ float crcp[128];
    const int t = threadIdx.x;
    float* wb = wbuf + (size_t)blockIdx.x * 16384;
    if (t < 128) {
        float ssum = 0.f;
        for (int q = 0; q < 128; ++q) ssum += expf(wb[q * 128 + t]);
        crcp[t] = 1.0f / ssum;
    }
    __syncthreads();
    for (int i = t; i < 16384; i += 256)
        wb[i] = expf(wb[i]) * crcp[i & 127];
}

// ---------------------------------------------------------------------------
// K4: mean_log[b,i,:] = sum_j soft[b,j,i] * LV[b,j,:]
// A = soft^T staged with transpose into LDS; B = LV streamed in 32-row chunks.
// Writes ML over the (dead) LQ region.
// ---------------------------------------------------------------------------
__global__ __launch_bounds__(256) void meanlog_kernel(
    const float* __restrict__ soft, const float* __restrict__ LV,
    float* __restrict__ ML)
{
    __shared__ float Wt[32 * 129];              // [i][j]
    __shared__ __align__(16) float Bl[32 * 260]; // [j][c]
    const int b  = blockIdx.z;
    const int i0 = blockIdx.y * 32;
    const int c0 = blockIdx.x * 256;
    const int t  = threadIdx.x;
    const float* sp = soft + (size_t)b * 16384;
#pragma unroll
    for (int jb = 0; jb < 4; ++jb) {
        int j  = jb * 32 + (t >> 3);
        int i4 = (t & 7) * 4;
        float4 v = *(const float4*)&sp[(size_t)j * 128 + i0 + i4];
        Wt[(i4 + 0) * 129 + j] = v.x;
        Wt[(i4 + 1) * 129 + j] = v.y;
        Wt[(i4 + 2) * 129 + j] = v.z;
        Wt[(i4 + 3) * 129 + j] = v.w;
    }
    float acc[32];
#pragma unroll
    for (int i = 0; i < 32; ++i) acc[i] = 0.f;
    const float* lv = LV + (size_t)2 * NM * 1024 + (size_t)b * 128 * 1024 + c0;
    for (int j0 = 0; j0 < 128; j0 += 32) {
        __syncthreads();   // covers Wt writes (first iter) + Bl reuse
#pragma unroll
        for (int jj8 = 0; jj8 < 8; ++jj8) {
            int j  = jj8 * 4 + (t >> 6);
            int c4 = (t & 63) * 4;
            *(float4*)&Bl[j * 260 + c4] =
                *(const float4*)&lv[(size_t)(j0 + j) * 1024 + c4];
        }
        __syncthreads();
#pragma unroll
        for (int jj = 0; jj < 32; ++jj) {
            float v = Bl[jj * 260 + t];
#pragma unroll
            for (int i = 0; i < 32; ++i)
                acc[i] = fmaf(Wt[i * 129 + j0 + jj], v, acc[i]);   // broadcast
        }
    }
    float* mp = ML + ((size_t)b * 128 + i0) * 1024 + c0;
#pragma unroll
    for (int i = 0; i < 32; ++i) mp[(size_t)i * 1024 + t] = acc[i];
}

// ---------------------------------------------------------------------------
// launcher
// ws layout (floats): [0, 3*NM*1024) qkv -> logs in place (region0 reused as ML)
//                     [+0, 16384)     ssq (qq,kk,(vv))
//                     [+, NM*128)     weights/soft (in-place softmax)
// total ~50.1 MB
// ---------------------------------------------------------------------------
extern "C" void kernel_launch(void* const* d_in, const int* in_sizes, int n_in,
                              void* d_out, int out_size, void* d_ws, size_t ws_size,
                              hipStream_t stream)
{
    const float* x  = (const float*)d_in[0];
    const float* Wq = (const float*)d_in[1];
    const float* Wk = (const float*)d_in[2];
    const float* Wv = (const float*)d_in[3];
    float* ws   = (float*)d_ws;
    float* qkv  = ws;                               // 3*NM*1024
    float* ssqp = ws + (size_t)3 * NM * 1024;       // 12288 (padded 16384)
    float* wbuf = ssqp + 16384;                     // NM*128
    float* out  = (float*)d_out;

    bimap_kernel<<<NM, 256, 0, stream>>>(x, Wq, Wk, Wv, qkv);
    eig_fn_kernel<0><<<NMAT3 / 2, 64, 0, stream>>>(qkv, qkv, ssqp, 0.0f);
    qk_weights_kernel<<<dim3(4, 4, 32), 256, 0, stream>>>(qkv, ssqp, wbuf);
    softmax_kernel<<<32, 256, 0, stream>>>(wbuf);
    meanlog_kernel<<<dim3(4, 4, 32), 256, 0, stream>>>(wbuf, qkv, qkv);
    eig_fn_kernel<1><<<NM / 2, 64, 0, stream>>>(qkv, out, nullptr, 16.0f);
}

// Round 3
// 1109.859 us; speedup vs baseline: 1.2860x; 1.0973x over previous
//
#include <hip/hip_runtime.h>
#include <math.h>

// Problem constants
#define NB   32
#define NP   128
#define NM   4096        // NB*NP matrices per type
#define NMAT3 12288      // 3*NM (Q,K,V)

// ---------------------------------------------------------------------------
// K1: bimap — Q/K/V[b,p] = W * x[b,p] * W^T   (x: 64x64 SPD, W: 32x64)
// ---------------------------------------------------------------------------
__global__ __launch_bounds__(256) void bimap_kernel(
    const float* __restrict__ x, const float* __restrict__ Wq,
    const float* __restrict__ Wk, const float* __restrict__ Wv,
    float* __restrict__ qkv)
{
    __shared__ __align__(16) float S[64 * 64];
    __shared__ float Wl[32 * 65];
    __shared__ float T[32 * 65];
    const int tid = threadIdx.x;
    const int bp  = blockIdx.x;
    const float* xs = x + (size_t)bp * 4096;
#pragma unroll
    for (int k = 0; k < 4; ++k) {
        int idx = tid * 4 + k * 1024;
        *(float4*)&S[idx] = *(const float4*)&xs[idx];
    }
    const int o32 = tid & 31;
    const int grp = tid >> 5;
#pragma unroll 1
    for (int w = 0; w < 3; ++w) {
        const float* Wsrc = (w == 0) ? Wq : ((w == 1) ? Wk : Wv);
        __syncthreads();
#pragma unroll
        for (int k = 0; k < 8; ++k) {
            int f = tid + k * 256;
            Wl[(f >> 6) * 65 + (f & 63)] = Wsrc[f];
        }
        __syncthreads();
        {
            float acc[8];
#pragma unroll
            for (int jj = 0; jj < 8; ++jj) acc[jj] = 0.f;
            const int j0 = grp * 8;
#pragma unroll 4
            for (int i = 0; i < 64; ++i) {
                float wv = Wl[o32 * 65 + i];
                const float4 s0 = *(const float4*)&S[i * 64 + j0];
                const float4 s1 = *(const float4*)&S[i * 64 + j0 + 4];
                acc[0] = fmaf(wv, s0.x, acc[0]);
                acc[1] = fmaf(wv, s0.y, acc[1]);
                acc[2] = fmaf(wv, s0.z, acc[2]);
                acc[3] = fmaf(wv, s0.w, acc[3]);
                acc[4] = fmaf(wv, s1.x, acc[4]);
                acc[5] = fmaf(wv, s1.y, acc[5]);
                acc[6] = fmaf(wv, s1.z, acc[6]);
                acc[7] = fmaf(wv, s1.w, acc[7]);
            }
#pragma unroll
            for (int jj = 0; jj < 8; ++jj) T[o32 * 65 + j0 + jj] = acc[jj];
        }
        __syncthreads();
        {
            float oacc[4] = {0.f, 0.f, 0.f, 0.f};
            const int kcol = tid & 31;
            const int ob   = grp * 4;
#pragma unroll 4
            for (int j = 0; j < 64; ++j) {
                float wv = Wl[kcol * 65 + j];
#pragma unroll
                for (int cc = 0; cc < 4; ++cc)
                    oacc[cc] = fmaf(T[(ob + cc) * 65 + j], wv, oacc[cc]);
            }
            float* dst = qkv + ((size_t)w * NM + bp) * 1024;
#pragma unroll
            for (int cc = 0; cc < 4; ++cc)
                dst[(ob + cc) * 32 + kcol] = oacc[cc];
        }
    }
}

// ---------------------------------------------------------------------------
// K2/K5: batched symmetric eig-function via BLOCKED one-sided (Hestenes)
// Jacobi. Each lane owns TWO columns (supercolumn s -> global cols s, s+16);
// 16 lanes per matrix, 4 matrices per wave64 block.
// XOR tournament over supercolumns: rounds m=1..15, partner lane = lane^m.
// Per round: exchange 2 columns (64 shfl) and resolve 4 column-pairs
// (halves DS volume per matrix vs 1-col/lane; R2 showed DS-bound).
// Both ends of a pair compute rotations from bitwise-identical expressions
// (fp mul commutes, same fma order, canonical p/q by global column index),
// and the pair orderings (AC,AD,BC,BD) vs (CA,CB,DA,DB) touch each pair at
// identical column states, so register copies never diverge.
//
// Convergence: gamma^2 > 1e-10*ap*aq (|cos|>1e-5). fp32 dot noise is
// gamma^2 ~ 1.2e-13*ap*aq, so quiescence is reachable (R2's 1e-12 was only
// 8x above noise and never quiesced -> always hit the sweep cap).
// MODE 0: f=log(lambda), writes ssq=||out||_F^2 (in==out allowed)
// MODE 1: input += shift*I on load, f=exp(lambda-shift)
// ---------------------------------------------------------------------------
__device__ __forceinline__ float dot2(const float (&x)[32], const float (&y)[32]) {
    float g0 = 0.f, g1 = 0.f;
#pragma unroll
    for (int i = 0; i < 32; i += 2) {
        g0 = fmaf(x[i], y[i], g0);
        g1 = fmaf(x[i + 1], y[i + 1], g1);
    }
    return g0 + g1;
}

__device__ __forceinline__ void jrot(float (&own)[32], float (&cop)[32],
                                     float& alO, float& alC, bool low,
                                     bool& anyrot) {
    const float gm = dot2(own, cop);
    const float ap = low ? alO : alC;
    const float aq = low ? alC : alO;
    const bool doRot = gm * gm > 1e-10f * (ap * aq);
    anyrot |= doRot;
    const float zeta = (aq - ap) / (2.0f * gm);
    float tt = copysignf(1.0f / (fabsf(zeta) + sqrtf(fmaf(zeta, zeta, 1.0f))), zeta);
    float cc = 1.0f / sqrtf(fmaf(tt, tt, 1.0f));
    float sn = cc * tt;
    if (!doRot) { cc = 1.0f; sn = 0.0f; }   // also rescues NaN when gm==0
    const float sO = low ? -sn : sn;
    const float sC = low ? sn : -sn;
#pragma unroll
    for (int i = 0; i < 32; ++i) {
        const float o = own[i], q = cop[i];
        own[i] = fmaf(cc, o, sO * q);
        cop[i] = fmaf(cc, q, sC * o);
    }
    const float c2 = cc * cc, s2 = sn * sn, cs2 = 2.0f * cc * sn * gm;
    const float apn = fmaf(c2, ap, fmaf(s2, aq, -cs2));
    const float aqn = fmaf(s2, ap, fmaf(c2, aq, cs2));
    alO = low ? apn : aqn;
    alC = low ? aqn : apn;
}

template <int MODE>
__global__ __launch_bounds__(64) void eig_fn_kernel(
    const float* in, float* out, float* __restrict__ ssq, float shift)
{
    __shared__ __align__(16) float Uld[2][32 * 36];
    __shared__ __align__(16) float fld[2][32];
    const int tid  = threadIdx.x;
    const int s16  = tid & 15;           // supercolumn
    const int slot = tid >> 4;           // matrix slot in block (0..3)
    const int cA   = s16, cB = s16 + 16; // owned global columns
    const size_t midx = (size_t)blockIdx.x * 4 + slot;

    const float* src = in + midx * 1024;
    float a[32], b[32];
#pragma unroll
    for (int i = 0; i < 32; ++i) {
        float va = src[i * 32 + cA];
        float vb = src[i * 32 + cB];
        if (MODE == 1) {
            va += (i == cA) ? shift : 0.0f;
            vb += (i == cB) ? shift : 0.0f;
        }
        a[i] = va; b[i] = vb;
    }

    // ---- blocked one-sided Jacobi sweeps ----
    for (int sweep = 0; sweep < 10; ++sweep) {
        float alA = dot2(a, a);
        float alB = dot2(b, b);
        bool anyrot = false;
        // intra-lane pair (cA, cB): cA < cB always
        jrot(a, b, alA, alB, true, anyrot);
        for (int m = 1; m < 16; ++m) {
            float tC[32], tD[32];
#pragma unroll
            for (int i = 0; i < 32; ++i) tC[i] = __shfl_xor(a[i], m);
#pragma unroll
            for (int i = 0; i < 32; ++i) tD[i] = __shfl_xor(b[i], m);
            float aC = __shfl_xor(alA, m);
            float aD = __shfl_xor(alB, m);
            const bool low1 = s16 < (s16 ^ m);   // cA vs partner cC; == cB vs cD
            jrot(a, tC, alA, aC, low1, anyrot);  // (s, s^m)
            jrot(a, tD, alA, aD, true, anyrot);  // (s, s^m+16): always low
            jrot(b, tC, alB, aC, false, anyrot); // (s+16, s^m): never low
            jrot(b, tD, alB, aD, low1, anyrot);  // (s+16, s^m+16)
        }
        if (!__any((int)anyrot)) break;
    }

    // ---- reconstruction: out = U f(S) U^T, two passes of 2 matrices ----
    const float s2A = dot2(a, a), s2B = dot2(b, b);
    const float sigA = sqrtf(s2A), sigB = sqrtf(s2B);
    const float invA = 1.0f / fmaxf(sigA, 1e-30f);
    const float invB = 1.0f / fmaxf(sigB, 1e-30f);
    float fvA, fvB;
    if (MODE == 0) {
        fvA = logf(fmaxf(sigA, 1e-38f));
        fvB = logf(fmaxf(sigB, 1e-38f));
    } else {
        fvA = expf(sigA - shift);
        fvB = expf(sigB - shift);
    }

    const int l5 = tid >> 5;   // matrix (within pass) for compute phase
    const int c  = tid & 31;   // output column for compute phase
#pragma unroll 1
    for (int pass = 0; pass < 2; ++pass) {
        __syncthreads();   // Uld reuse between passes
        if ((slot >> 1) == pass) {
            const int sl = slot & 1;
#pragma unroll
            for (int i = 0; i < 32; ++i) {
                Uld[sl][i * 36 + cA] = a[i] * invA;   // banks: 32 distinct c
                Uld[sl][i * 36 + cB] = b[i] * invB;
            }
            fld[sl][cA] = fvA;
            fld[sl][cB] = fvB;
        }
        __syncthreads();
        const size_t mloc = (size_t)blockIdx.x * 4 + pass * 2 + l5;
        // rr[m] = f[m] * U[c][m]
        float rr[32];
        {
            const float4* urow = (const float4*)&Uld[l5][c * 36];  // 144B-aligned
            const float4* frow = (const float4*)&fld[l5][0];
#pragma unroll
            for (int m4 = 0; m4 < 8; ++m4) {
                float4 u4 = urow[m4];
                float4 f4 = frow[m4];
                rr[m4 * 4 + 0] = u4.x * f4.x;
                rr[m4 * 4 + 1] = u4.y * f4.y;
                rr[m4 * 4 + 2] = u4.z * f4.z;
                rr[m4 * 4 + 3] = u4.w * f4.w;
            }
        }
        float* dst = out + mloc * 1024;
        float sq = 0.f;
#pragma unroll
        for (int i = 0; i < 32; ++i) {
            float acc = 0.f;
            const float4* urow = (const float4*)&Uld[l5][i * 36];  // broadcast
#pragma unroll
            for (int m4 = 0; m4 < 8; ++m4) {
                float4 u4 = urow[m4];
                acc = fmaf(u4.x, rr[m4 * 4 + 0], acc);
                acc = fmaf(u4.y, rr[m4 * 4 + 1], acc);
                acc = fmaf(u4.z, rr[m4 * 4 + 2], acc);
                acc = fmaf(u4.w, rr[m4 * 4 + 3], acc);
            }
            dst[i * 32 + c] = acc;    // coalesced
            sq = fmaf(acc, acc, sq);
        }
        if (MODE == 0) {
#pragma unroll
            for (int off = 1; off < 32; off <<= 1) sq += __shfl_xor(sq, off);
            if (c == 0) ssq[mloc] = sq;
        }
    }
}

// ---------------------------------------------------------------------------
// K3a: weights[b,q,k] = 1/(1+log1p(max(qq+kk-2*<LQ_q,LK_k>_F, 0)))
// ---------------------------------------------------------------------------
__global__ __launch_bounds__(256) void qk_weights_kernel(
    const float* __restrict__ L, const float* __restrict__ ssq,
    float* __restrict__ wbuf)
{
    __shared__ float Aq[32 * 37];
    __shared__ float Bk[32 * 37];
    const int b  = blockIdx.z;
    const int q0 = blockIdx.y * 32;
    const int k0 = blockIdx.x * 32;
    const int tid = threadIdx.x;
    const int tx = tid & 15, ty = tid >> 4;
    const float* LQ = L + ((size_t)b * 128 + q0) * 1024;
    const float* LK = L + (size_t)NM * 1024 + ((size_t)b * 128 + k0) * 1024;
    const int lrow = tid >> 3;
    const int lm4  = (tid & 7) * 4;
    float acc00 = 0, acc01 = 0, acc10 = 0, acc11 = 0;
    for (int m0 = 0; m0 < 1024; m0 += 32) {
        __syncthreads();
        float4 va = *(const float4*)&LQ[(size_t)lrow * 1024 + m0 + lm4];
        float4 vb = *(const float4*)&LK[(size_t)lrow * 1024 + m0 + lm4];
        Aq[lrow * 37 + lm4 + 0] = va.x; Aq[lrow * 37 + lm4 + 1] = va.y;
        Aq[lrow * 37 + lm4 + 2] = va.z; Aq[lrow * 37 + lm4 + 3] = va.w;
        Bk[lrow * 37 + lm4 + 0] = vb.x; Bk[lrow * 37 + lm4 + 1] = vb.y;
        Bk[lrow * 37 + lm4 + 2] = vb.z; Bk[lrow * 37 + lm4 + 3] = vb.w;
        __syncthreads();
#pragma unroll
        for (int mm = 0; mm < 32; ++mm) {
            float a0 = Aq[(ty * 2 + 0) * 37 + mm];
            float a1 = Aq[(ty * 2 + 1) * 37 + mm];
            float b0 = Bk[(tx * 2 + 0) * 37 + mm];
            float b1 = Bk[(tx * 2 + 1) * 37 + mm];
            acc00 = fmaf(a0, b0, acc00); acc01 = fmaf(a0, b1, acc01);
            acc10 = fmaf(a1, b0, acc10); acc11 = fmaf(a1, b1, acc11);
        }
    }
    const float* qqp = ssq + (size_t)b * 128 + q0;
    const float* kkp = ssq + NM + (size_t)b * 128 + k0;
    const int q = ty * 2, k = tx * 2;
    float* wrow0 = wbuf + ((size_t)b * 128 + q0 + q) * 128 + k0 + k;
    float* wrow1 = wrow0 + 128;
    float e;
    e = fmaxf(qqp[q] + kkp[k] - 2.0f * acc00, 0.0f);
    wrow0[0] = 1.0f / (1.0f + log1pf(e));
    e = fmaxf(qqp[q] + kkp[k + 1] - 2.0f * acc01, 0.0f);
    wrow0[1] = 1.0f / (1.0f + log1pf(e));
    e = fmaxf(qqp[q + 1] + kkp[k] - 2.0f * acc10, 0.0f);
    wrow1[0] = 1.0f / (1.0f + log1pf(e));
    e = fmaxf(qqp[q + 1] + kkp[k + 1] - 2.0f * acc11, 0.0f);
    wrow1[1] = 1.0f / (1.0f + log1pf(e));
}

// ---------------------------------------------------------------------------
// K3b: in-place softmax over the QUERY axis (column-wise on [q][k])
// ---------------------------------------------------------------------------
__global__ __launch_bounds__(256) void softmax_kernel(float* __restrict__ wbuf)
{
    __shared__ float crcp[128];
    const int t = threadIdx.x;
    float* wb = wbuf + (size_t)blockIdx.x * 16384;
    if (t < 128) {
        float ssum = 0.f;
        for (int q = 0; q < 128; ++q) ssum += expf(wb[q * 128 + t]);
        crcp[t] = 1.0f / ssum;
    }
    __syncthreads();
    for (int i = t; i < 16384; i += 256)
        wb[i] = expf(wb[i]) * crcp[i & 127];
}

// ---------------------------------------------------------------------------
// K4: mean_log[b,i,:] = sum_j soft[b,j,i] * LV[b,j,:]
// ---------------------------------------------------------------------------
__global__ __launch_bounds__(256) void meanlog_kernel(
    const float* __restrict__ soft, const float* __restrict__ LV,
    float* __restrict__ ML)
{
    __shared__ float Wt[32 * 129];
    __shared__ __align__(16) float Bl[32 * 260];
    const int b  = blockIdx.z;
    const int i0 = blockIdx.y * 32;
    const int c0 = blockIdx.x * 256;
    const int t  = threadIdx.x;
    const float* sp = soft + (size_t)b * 16384;
#pragma unroll
    for (int jb = 0; jb < 4; ++jb) {
        int j  = jb * 32 + (t >> 3);
        int i4 = (t & 7) * 4;
        float4 v = *(const float4*)&sp[(size_t)j * 128 + i0 + i4];
        Wt[(i4 + 0) * 129 + j] = v.x;
        Wt[(i4 + 1) * 129 + j] = v.y;
        Wt[(i4 + 2) * 129 + j] = v.z;
        Wt[(i4 + 3) * 129 + j] = v.w;
    }
    float acc[32];
#pragma unroll
    for (int i = 0; i < 32; ++i) acc[i] = 0.f;
    const float* lv = LV + (size_t)2 * NM * 1024 + (size_t)b * 128 * 1024 + c0;
    for (int j0 = 0; j0 < 128; j0 += 32) {
        __syncthreads();
#pragma unroll
        for (int jj8 = 0; jj8 < 8; ++jj8) {
            int j  = jj8 * 4 + (t >> 6);
            int c4 = (t & 63) * 4;
            *(float4*)&Bl[j * 260 + c4] =
                *(const float4*)&lv[(size_t)(j0 + j) * 1024 + c4];
        }
        __syncthreads();
#pragma unroll
        for (int jj = 0; jj < 32; ++jj) {
            float v = Bl[jj * 260 + t];
#pragma unroll
            for (int i = 0; i < 32; ++i)
                acc[i] = fmaf(Wt[i * 129 + j0 + jj], v, acc[i]);
        }
    }
    float* mp = ML + ((size_t)b * 128 + i0) * 1024 + c0;
#pragma unroll
    for (int i = 0; i < 32; ++i) mp[(size_t)i * 1024 + t] = acc[i];
}

// ---------------------------------------------------------------------------
// launcher
// ---------------------------------------------------------------------------
extern "C" void kernel_launch(void* const* d_in, const int* in_sizes, int n_in,
                              void* d_out, int out_size, void* d_ws, size_t ws_size,
                              hipStream_t stream)
{
    const float* x  = (const float*)d_in[0];
    const float* Wq = (const float*)d_in[1];
    const float* Wk = (const float*)d_in[2];
    const float* Wv = (const float*)d_in[3];
    float* ws   = (float*)d_ws;
    float* qkv  = ws;                               // 3*NM*1024
    float* ssqp = ws + (size_t)3 * NM * 1024;       // 12288 (padded 16384)
    float* wbuf = ssqp + 16384;                     // NM*128
    float* out  = (float*)d_out;

    bimap_kernel<<<NM, 256, 0, stream>>>(x, Wq, Wk, Wv, qkv);
    eig_fn_kernel<0><<<NMAT3 / 4, 64, 0, stream>>>(qkv, qkv, ssqp, 0.0f);
    qk_weights_kernel<<<dim3(4, 4, 32), 256, 0, stream>>>(qkv, ssqp, wbuf);
    softmax_kernel<<<32, 256, 0, stream>>>(wbuf);
    meanlog_kernel<<<dim3(4, 4, 32), 256, 0, stream>>>(wbuf, qkv, qkv);
    eig_fn_kernel<1><<<NM / 4, 64, 0, stream>>>(qkv, out, nullptr, 16.0f);
}